// Round 1
// baseline (2211.810 us; speedup 1.0000x reference)
//
#include <hip/hip_runtime.h>
#include <math.h>

#define NH 16
#define DK 64
#define DC 256
#define DM 1024
#define BB 2
#define SS 2048
#define TT (BB*SS)

// Generic C[M,N] = A[M,K] @ W[K,N], fp32, 64x64 tile, BK=16, 4x4 per thread.
__global__ __launch_bounds__(256) void gemm64(const float* __restrict__ A,
                                              const float* __restrict__ W,
                                              float* __restrict__ C,
                                              int M, int N, int K) {
    __shared__ float As[16][65];   // As[k][m]
    __shared__ float Ws[16][65];   // Ws[k][n]
    const int bm = blockIdx.y * 64;
    const int bn = blockIdx.x * 64;
    const int tid = threadIdx.x;
    const int tr = tid >> 4;          // 0..15
    const int tc = tid & 15;          // 0..15
    const int lm = tid >> 2;          // 0..63  (A row)
    const int lk = (tid & 3) << 2;    // 0,4,8,12 (A k-chunk)
    const int wk = tid >> 4;          // 0..15 (W k-row)
    const int wc = (tid & 15) << 2;   // 0..60 (W col chunk)

    float acc[4][4] = {};
    for (int k0 = 0; k0 < K; k0 += 16) {
        float4 av = *reinterpret_cast<const float4*>(&A[(bm + lm) * K + k0 + lk]);
        float4 wv = *reinterpret_cast<const float4*>(&W[(k0 + wk) * N + bn + wc]);
        As[lk + 0][lm] = av.x;
        As[lk + 1][lm] = av.y;
        As[lk + 2][lm] = av.z;
        As[lk + 3][lm] = av.w;
        Ws[wk][wc + 0] = wv.x;
        Ws[wk][wc + 1] = wv.y;
        Ws[wk][wc + 2] = wv.z;
        Ws[wk][wc + 3] = wv.w;
        __syncthreads();
        #pragma unroll
        for (int kk = 0; kk < 16; ++kk) {
            float a0 = As[kk][tr * 4 + 0];
            float a1 = As[kk][tr * 4 + 1];
            float a2 = As[kk][tr * 4 + 2];
            float a3 = As[kk][tr * 4 + 3];
            float b0 = Ws[kk][tc * 4 + 0];
            float b1 = Ws[kk][tc * 4 + 1];
            float b2 = Ws[kk][tc * 4 + 2];
            float b3 = Ws[kk][tc * 4 + 3];
            acc[0][0] += a0 * b0; acc[0][1] += a0 * b1; acc[0][2] += a0 * b2; acc[0][3] += a0 * b3;
            acc[1][0] += a1 * b0; acc[1][1] += a1 * b1; acc[1][2] += a1 * b2; acc[1][3] += a1 * b3;
            acc[2][0] += a2 * b0; acc[2][1] += a2 * b1; acc[2][2] += a2 * b2; acc[2][3] += a2 * b3;
            acc[3][0] += a3 * b0; acc[3][1] += a3 * b1; acc[3][2] += a3 * b2; acc[3][3] += a3 * b3;
        }
        __syncthreads();
    }
    #pragma unroll
    for (int i = 0; i < 4; ++i) {
        float4 ov;
        ov.x = acc[i][0]; ov.y = acc[i][1]; ov.z = acc[i][2]; ov.w = acc[i][3];
        *reinterpret_cast<float4*>(&C[(bm + tr * 4 + i) * N + bn + tc * 4]) = ov;
    }
}

// Causal flash attention, fp32. One block = one (b, h, 64-row q tile).
// Q/K/V layout: [B*S, NH*DK] row-major (head h at column offset h*DK).
__global__ __launch_bounds__(256) void attn64(const float* __restrict__ Q,
                                              const float* __restrict__ K,
                                              const float* __restrict__ V,
                                              float* __restrict__ O) {
    __shared__ float Qs[64][65];
    __shared__ float Ks[64][65];   // reused as P after scores are consumed
    __shared__ float Vs[64][65];
    const int qt = blockIdx.x;            // 0..31
    const int h  = blockIdx.y;            // 0..15
    const int b  = blockIdx.z;            // 0..1
    const int tid = threadIdx.x;
    const int r  = tid >> 2;              // row in tile 0..63
    const int dq = (tid & 3) << 4;        // 16-wide dim/col chunk base
    const int q0 = qt * 64;
    const int rowstride = NH * DK;        // 1024
    const int base = b * SS * rowstride + h * DK;

    // load Q tile
    #pragma unroll
    for (int j = 0; j < 16; j += 4) {
        float4 v = *reinterpret_cast<const float4*>(&Q[base + (q0 + r) * rowstride + dq + j]);
        Qs[r][dq + j + 0] = v.x; Qs[r][dq + j + 1] = v.y;
        Qs[r][dq + j + 2] = v.z; Qs[r][dq + j + 3] = v.w;
    }

    float acc[16] = {};
    float m = -1e30f, l = 0.f;

    for (int kt = 0; kt <= qt; ++kt) {
        __syncthreads();   // protect Ks/Vs from previous iteration's readers
        const int k0 = kt * 64;
        #pragma unroll
        for (int j = 0; j < 16; j += 4) {
            float4 kv = *reinterpret_cast<const float4*>(&K[base + (k0 + r) * rowstride + dq + j]);
            Ks[r][dq + j + 0] = kv.x; Ks[r][dq + j + 1] = kv.y;
            Ks[r][dq + j + 2] = kv.z; Ks[r][dq + j + 3] = kv.w;
            float4 vv = *reinterpret_cast<const float4*>(&V[base + (k0 + r) * rowstride + dq + j]);
            Vs[r][dq + j + 0] = vv.x; Vs[r][dq + j + 1] = vv.y;
            Vs[r][dq + j + 2] = vv.z; Vs[r][dq + j + 3] = vv.w;
        }
        __syncthreads();

        // scores: row r, cols c = dq..dq+15
        float s[16];
        #pragma unroll
        for (int i = 0; i < 16; ++i) s[i] = 0.f;
        for (int d = 0; d < 64; ++d) {
            float qv = Qs[r][d];
            #pragma unroll
            for (int i = 0; i < 16; ++i) s[i] += qv * Ks[dq + i][d];
        }
        const int qg = q0 + r;
        #pragma unroll
        for (int i = 0; i < 16; ++i) {
            int kg = k0 + dq + i;
            s[i] = (kg <= qg) ? s[i] * 0.125f : -1e30f;
        }
        // row max across this thread's 16 + the 4 lanes of this row (consecutive lanes)
        float tm = s[0];
        #pragma unroll
        for (int i = 1; i < 16; ++i) tm = fmaxf(tm, s[i]);
        tm = fmaxf(tm, __shfl_xor(tm, 1));
        tm = fmaxf(tm, __shfl_xor(tm, 2));
        float mnew = fmaxf(m, tm);
        float scale = __expf(m - mnew);
        float rowsum = 0.f;
        #pragma unroll
        for (int i = 0; i < 16; ++i) {
            float p = __expf(s[i] - mnew);
            s[i] = p;
            rowsum += p;
        }
        rowsum += __shfl_xor(rowsum, 1);
        rowsum += __shfl_xor(rowsum, 2);
        l = l * scale + rowsum;
        m = mnew;
        #pragma unroll
        for (int i = 0; i < 16; ++i) acc[i] *= scale;

        __syncthreads();   // everyone done reading Ks as scores input
        #pragma unroll
        for (int i = 0; i < 16; ++i) Ks[r][dq + i] = s[i];   // P tile aliases Ks
        __syncthreads();

        // O[r][dq+i] += sum_j P[r][j] * V[j][dq+i]
        for (int j = 0; j < 64; ++j) {
            float p = Ks[r][j];
            #pragma unroll
            for (int i = 0; i < 16; ++i) acc[i] += p * Vs[j][dq + i];
        }
    }

    float inv = 1.f / l;
    #pragma unroll
    for (int i = 0; i < 16; i += 4) {
        float4 ov;
        ov.x = acc[i + 0] * inv; ov.y = acc[i + 1] * inv;
        ov.z = acc[i + 2] * inv; ov.w = acc[i + 3] * inv;
        *reinterpret_cast<float4*>(&O[base + (q0 + r) * rowstride + dq + i]) = ov;
    }
}

extern "C" void kernel_launch(void* const* d_in, const int* in_sizes, int n_in,
                              void* d_out, int out_size, void* d_ws, size_t ws_size,
                              hipStream_t stream) {
    const float* x     = (const float*)d_in[0];
    const float* W_dq  = (const float*)d_in[1];
    const float* W_uq  = (const float*)d_in[2];
    const float* W_dkv = (const float*)d_in[3];
    const float* W_uk  = (const float*)d_in[4];
    const float* W_uv  = (const float*)d_in[5];
    const float* W_o   = (const float*)d_in[6];
    float* out = (float*)d_out;

    float* ws = (float*)d_ws;
    // layout (floats): Q[4194304] K[4194304] V[4194304] c_q[1048576] c_kv[1048576]
    // attno reuses the c_q/c_kv region (dead by then).
    float* Qb    = ws;
    float* Kb    = ws + 4194304;
    float* Vb    = ws + 8388608;
    float* c_q   = ws + 12582912;
    float* c_kv  = ws + 13631488;
    float* attno = ws + 12582912;   // 4194304 floats, overwrites c_q/c_kv

    dim3 blk(256);
    // c_q = x @ W_dq          [4096,1024]x[1024,256]
    gemm64<<<dim3(DC / 64, TT / 64), blk, 0, stream>>>(x, W_dq, c_q, TT, DC, DM);
    // c_kv = x @ W_dkv
    gemm64<<<dim3(DC / 64, TT / 64), blk, 0, stream>>>(x, W_dkv, c_kv, TT, DC, DM);
    // Q = c_q @ W_uq          [4096,256]x[256,1024]
    gemm64<<<dim3(DM / 64, TT / 64), blk, 0, stream>>>(c_q, W_uq, Qb, TT, DM, DC);
    // K = c_kv @ W_uk
    gemm64<<<dim3(DM / 64, TT / 64), blk, 0, stream>>>(c_kv, W_uk, Kb, TT, DM, DC);
    // V = c_kv @ W_uv
    gemm64<<<dim3(DM / 64, TT / 64), blk, 0, stream>>>(c_kv, W_uv, Vb, TT, DM, DC);
    // attention
    attn64<<<dim3(SS / 64, NH, BB), blk, 0, stream>>>(Qb, Kb, Vb, attno);
    // out = attno @ W_o       [4096,1024]x[1024,1024]
    gemm64<<<dim3(DM / 64, TT / 64), blk, 0, stream>>>(attno, W_o, out, TT, DM, DM);
}

// Round 2
// 222.482 us; speedup vs baseline: 9.9415x; 9.9415x over previous
//
#include <hip/hip_runtime.h>
#include <math.h>

#define AS3 __attribute__((address_space(3)))
#define AS1 __attribute__((address_space(1)))

typedef unsigned short u16;
typedef __bf16 bf16_t;
typedef bf16_t bf16x8 __attribute__((ext_vector_type(8)));
typedef float f32x4 __attribute__((ext_vector_type(4)));
typedef unsigned short u16x8 __attribute__((ext_vector_type(8)));

#define NH 16
#define DK 64
#define DC 256
#define DM 1024
#define BB 2
#define SS 2048
#define TT (BB*SS)

__device__ __forceinline__ u16 f2bf(float f) {
    unsigned u = __builtin_bit_cast(unsigned, f);
    unsigned r = (u + 0x7FFFu + ((u >> 16) & 1u)) >> 16;
    return (u16)r;
}

// ---------------- prep kernels ----------------

__global__ __launch_bounds__(256) void cvt_f32_bf16(const float* __restrict__ in,
                                                    u16* __restrict__ out, int n) {
    int i = (blockIdx.x * 256 + threadIdx.x) * 8;
    if (i >= n) return;
    float4 v0 = *reinterpret_cast<const float4*>(in + i);
    float4 v1 = *reinterpret_cast<const float4*>(in + i + 4);
    u16x8 o;
    o[0] = f2bf(v0.x); o[1] = f2bf(v0.y); o[2] = f2bf(v0.z); o[3] = f2bf(v0.w);
    o[4] = f2bf(v1.x); o[5] = f2bf(v1.y); o[6] = f2bf(v1.z); o[7] = f2bf(v1.w);
    *reinterpret_cast<u16x8*>(out + i) = o;
}

// out[(c + orow_off)*opitch + r] = bf16(in[r*C + c])
__global__ __launch_bounds__(256) void transpose_cvt(const float* __restrict__ in, int R, int C,
                                                     u16* __restrict__ out, int opitch, int orow_off) {
    __shared__ float t[32][33];
    int c0 = blockIdx.x * 32, r0 = blockIdx.y * 32;
    int tx = threadIdx.x & 31, ty = threadIdx.x >> 5;   // ty 0..7
    #pragma unroll
    for (int p = 0; p < 4; ++p)
        t[ty + 8 * p][tx] = in[(r0 + ty + 8 * p) * C + c0 + tx];
    __syncthreads();
    #pragma unroll
    for (int p = 0; p < 4; ++p)
        out[(c0 + ty + 8 * p + orow_off) * opitch + r0 + tx] = f2bf(t[tx][ty + 8 * p]);
}

// out[c*opitch + r] = in[r*ipitch + c]   (u16)
__global__ __launch_bounds__(256) void transpose_u16(const u16* __restrict__ in, int ipitch,
                                                     u16* __restrict__ out, int opitch) {
    __shared__ u16 t[32][34];
    int c0 = blockIdx.x * 32, r0 = blockIdx.y * 32;
    int tx = threadIdx.x & 31, ty = threadIdx.x >> 5;
    #pragma unroll
    for (int p = 0; p < 4; ++p)
        t[ty + 8 * p][tx] = in[(r0 + ty + 8 * p) * ipitch + c0 + tx];
    __syncthreads();
    #pragma unroll
    for (int p = 0; p < 4; ++p)
        out[(c0 + ty + 8 * p) * opitch + r0 + tx] = t[tx][ty + 8 * p];
}

// ---------------- MFMA GEMM: C[M,N] = A[M,K] @ Bt[N,K]^T ----------------
// 128x128 tile, BK=32, 4 waves (2x2), each wave 4x4 frags of 16x16.
template <bool OUT_BF16>
__global__ __launch_bounds__(256) void gemm128(const u16* __restrict__ A, int lda,
                                               const u16* __restrict__ Bt, int ldb,
                                               void* __restrict__ C, int ldc, int K) {
    __shared__ u16 As[128 * 32];
    __shared__ u16 Bs[128 * 32];
    const int tid = threadIdx.x;
    const int lane = tid & 63;
    const int w = tid >> 6;
    const int wr = w >> 1, wc = w & 1;
    const int bm = blockIdx.y * 128, bn = blockIdx.x * 128;
    const int l15 = lane & 15, l4 = lane >> 4;

    f32x4 acc[4][4] = {};

    for (int k0 = 0; k0 < K; k0 += 32) {
        #pragma unroll
        for (int i = 0; i < 2; ++i) {
            int db = i * 4096 + w * 1024 + lane * 16;   // dest byte (incl lane part)
            int row = db >> 6;
            int kc = (db & 63) >> 1;
            __builtin_amdgcn_global_load_lds(
                (const AS1 void*)(A + (bm + row) * lda + k0 + kc),
                (AS3 void*)((AS3 char*)(AS3 void*)As + i * 4096 + w * 1024), 16, 0, 0);
            __builtin_amdgcn_global_load_lds(
                (const AS1 void*)(Bt + (bn + row) * ldb + k0 + kc),
                (AS3 void*)((AS3 char*)(AS3 void*)Bs + i * 4096 + w * 1024), 16, 0, 0);
        }
        __syncthreads();
        bf16x8 a[4], b[4];
        #pragma unroll
        for (int m = 0; m < 4; ++m)
            a[m] = __builtin_bit_cast(bf16x8,
                *reinterpret_cast<const u16x8*>(&As[(wr * 64 + m * 16 + l15) * 32 + l4 * 8]));
        #pragma unroll
        for (int n = 0; n < 4; ++n)
            b[n] = __builtin_bit_cast(bf16x8,
                *reinterpret_cast<const u16x8*>(&Bs[(wc * 64 + n * 16 + l15) * 32 + l4 * 8]));
        #pragma unroll
        for (int m = 0; m < 4; ++m)
            #pragma unroll
            for (int n = 0; n < 4; ++n)
                acc[m][n] = __builtin_amdgcn_mfma_f32_16x16x32_bf16(a[m], b[n], acc[m][n], 0, 0, 0);
        __syncthreads();
    }
    #pragma unroll
    for (int m = 0; m < 4; ++m) {
        int row = bm + wr * 64 + m * 16 + l4 * 4;
        #pragma unroll
        for (int j = 0; j < 4; ++j) {
            #pragma unroll
            for (int n = 0; n < 4; ++n) {
                int col = bn + wc * 64 + n * 16 + l15;
                if (OUT_BF16)
                    ((u16*)C)[(row + j) * ldc + col] = f2bf(acc[m][n][j]);
                else
                    ((float*)C)[(row + j) * ldc + col] = acc[m][n][j];
            }
        }
    }
}

// ---------------- MFMA causal flash attention ----------------
// Block = (qt, h, b): 64 q-rows, 4 waves x 16 rows. K-tile 64.
// Qb: [4096][1024] bf16 ; KVb: [4096][2048] bf16 (K in cols 0..1023)
// VtG: [2048][2048] bf16 = [b*16+h][dk 64][s 2048] ; O: [4096][1024] bf16
__global__ __launch_bounds__(256) void attn_mfma(const u16* __restrict__ Qb,
                                                 const u16* __restrict__ KVb,
                                                 const u16* __restrict__ VtG,
                                                 u16* __restrict__ O) {
    __shared__ u16 Ks[64 * 72];
    __shared__ u16 Vts[64 * 72];
    __shared__ u16 Ps[4][16 * 72];
    const int qt = blockIdx.x, h = blockIdx.y, b = blockIdx.z;
    const int tid = threadIdx.x, lane = tid & 63, w = tid >> 6;
    const int l15 = lane & 15, l4 = lane >> 4;
    const int q0 = qt * 64;
    const int bh = b * 16 + h;

    // hoisted Q fragments (A operand): row = l15 within wave's 16 q-rows
    const u16* qp = Qb + (b * SS + q0 + w * 16 + l15) * 1024 + h * 64 + l4 * 8;
    bf16x8 aq0 = __builtin_bit_cast(bf16x8, *reinterpret_cast<const u16x8*>(qp));
    bf16x8 aq1 = __builtin_bit_cast(bf16x8, *reinterpret_cast<const u16x8*>(qp + 32));

    f32x4 acc_o[4] = {};
    float mrow[4], lrow[4];
    #pragma unroll
    for (int j = 0; j < 4; ++j) { mrow[j] = -3.0e38f; lrow[j] = 0.f; }

    const int srow = tid >> 2;          // staging row 0..63
    const int scol = (tid & 3) * 16;    // staging col chunk
    const float c2 = 0.125f * 1.44269504088896340736f;  // scale * log2(e)

    for (int kt = 0; kt <= qt; ++kt) {
        const int k0 = kt * 64;
        __syncthreads();
        {   // stage K tile [key][dk] and Vt tile [dk][key]
            const u16* kp = KVb + (b * SS + k0 + srow) * 2048 + h * 64 + scol;
            u16x8 v0 = *reinterpret_cast<const u16x8*>(kp);
            u16x8 v1 = *reinterpret_cast<const u16x8*>(kp + 8);
            *reinterpret_cast<u16x8*>(&Ks[srow * 72 + scol]) = v0;
            *reinterpret_cast<u16x8*>(&Ks[srow * 72 + scol + 8]) = v1;
            const u16* vp = VtG + (bh * 64 + srow) * 2048 + k0 + scol;
            u16x8 w0 = *reinterpret_cast<const u16x8*>(vp);
            u16x8 w1 = *reinterpret_cast<const u16x8*>(vp + 8);
            *reinterpret_cast<u16x8*>(&Vts[srow * 72 + scol]) = w0;
            *reinterpret_cast<u16x8*>(&Vts[srow * 72 + scol + 8]) = w1;
        }
        __syncthreads();

        // S = Q K^T  (raw, scale folded into exp)
        f32x4 s[4];
        #pragma unroll
        for (int nb = 0; nb < 4; ++nb) {
            bf16x8 bk0 = __builtin_bit_cast(bf16x8,
                *reinterpret_cast<const u16x8*>(&Ks[(nb * 16 + l15) * 72 + l4 * 8]));
            bf16x8 bk1 = __builtin_bit_cast(bf16x8,
                *reinterpret_cast<const u16x8*>(&Ks[(nb * 16 + l15) * 72 + 32 + l4 * 8]));
            f32x4 z = {};
            z = __builtin_amdgcn_mfma_f32_16x16x32_bf16(aq0, bk0, z, 0, 0, 0);
            s[nb] = __builtin_amdgcn_mfma_f32_16x16x32_bf16(aq1, bk1, z, 0, 0, 0);
        }
        if (kt == qt) {  // causal mask, diagonal tile only
            #pragma unroll
            for (int nb = 0; nb < 4; ++nb) {
                int key = nb * 16 + l15;
                #pragma unroll
                for (int j = 0; j < 4; ++j) {
                    int q = w * 16 + l4 * 4 + j;
                    if (key > q) s[nb][j] = -3.0e38f;
                }
            }
        }
        // online softmax (rows live across lanes 0..15 of each 16-group)
        float pmax[4], scale[4], rsum[4];
        #pragma unroll
        for (int j = 0; j < 4; ++j) {
            float t = fmaxf(fmaxf(s[0][j], s[1][j]), fmaxf(s[2][j], s[3][j]));
            t = fmaxf(t, __shfl_xor(t, 1));
            t = fmaxf(t, __shfl_xor(t, 2));
            t = fmaxf(t, __shfl_xor(t, 4));
            t = fmaxf(t, __shfl_xor(t, 8));
            pmax[j] = t;
        }
        #pragma unroll
        for (int j = 0; j < 4; ++j) {
            float mnew = fmaxf(mrow[j], pmax[j]);
            scale[j] = exp2f((mrow[j] - mnew) * c2);
            mrow[j] = mnew;
            rsum[j] = 0.f;
        }
        #pragma unroll
        for (int nb = 0; nb < 4; ++nb)
            #pragma unroll
            for (int j = 0; j < 4; ++j) {
                float p = exp2f((s[nb][j] - mrow[j]) * c2);
                s[nb][j] = p;
                rsum[j] += p;
            }
        #pragma unroll
        for (int j = 0; j < 4; ++j) {
            float t = rsum[j];
            t += __shfl_xor(t, 1);
            t += __shfl_xor(t, 2);
            t += __shfl_xor(t, 4);
            t += __shfl_xor(t, 8);
            lrow[j] = lrow[j] * scale[j] + t;
        }
        // P -> LDS (per-wave region; wave-internal ordering only)
        #pragma unroll
        for (int nb = 0; nb < 4; ++nb)
            #pragma unroll
            for (int j = 0; j < 4; ++j)
                Ps[w][(l4 * 4 + j) * 72 + nb * 16 + l15] = f2bf(s[nb][j]);
        asm volatile("s_waitcnt lgkmcnt(0)" ::: "memory");
        __builtin_amdgcn_sched_barrier(0);
        // O += P @ V
        bf16x8 pa0 = __builtin_bit_cast(bf16x8,
            *reinterpret_cast<const u16x8*>(&Ps[w][l15 * 72 + l4 * 8]));
        bf16x8 pa1 = __builtin_bit_cast(bf16x8,
            *reinterpret_cast<const u16x8*>(&Ps[w][l15 * 72 + 32 + l4 * 8]));
        #pragma unroll
        for (int nb = 0; nb < 4; ++nb) {
            bf16x8 bv0 = __builtin_bit_cast(bf16x8,
                *reinterpret_cast<const u16x8*>(&Vts[(nb * 16 + l15) * 72 + l4 * 8]));
            bf16x8 bv1 = __builtin_bit_cast(bf16x8,
                *reinterpret_cast<const u16x8*>(&Vts[(nb * 16 + l15) * 72 + 32 + l4 * 8]));
            #pragma unroll
            for (int j = 0; j < 4; ++j) acc_o[nb][j] *= scale[j];
            acc_o[nb] = __builtin_amdgcn_mfma_f32_16x16x32_bf16(pa0, bv0, acc_o[nb], 0, 0, 0);
            acc_o[nb] = __builtin_amdgcn_mfma_f32_16x16x32_bf16(pa1, bv1, acc_o[nb], 0, 0, 0);
        }
    }
    #pragma unroll
    for (int nb = 0; nb < 4; ++nb)
        #pragma unroll
        for (int j = 0; j < 4; ++j) {
            int q = q0 + w * 16 + l4 * 4 + j;
            O[(b * SS + q) * 1024 + h * 64 + nb * 16 + l15] = f2bf(acc_o[nb][j] / lrow[j]);
        }
}

// ---------------- launch ----------------

extern "C" void kernel_launch(void* const* d_in, const int* in_sizes, int n_in,
                              void* d_out, int out_size, void* d_ws, size_t ws_size,
                              hipStream_t stream) {
    const float* x     = (const float*)d_in[0];
    const float* W_dq  = (const float*)d_in[1];
    const float* W_uq  = (const float*)d_in[2];
    const float* W_dkv = (const float*)d_in[3];
    const float* W_uk  = (const float*)d_in[4];
    const float* W_uv  = (const float*)d_in[5];
    const float* W_o   = (const float*)d_in[6];
    float* out = (float*)d_out;

    char* ws = (char*)d_ws;
    u16* xb      = (u16*)(ws);                          // 8 MB   [4096][1024]
    u16* c_qkv   = (u16*)(ws + (8u << 20));             // 4 MB   [4096][512]
    u16* Qb      = (u16*)(ws + (12u << 20));            // 8 MB   [4096][1024]
    u16* KVb     = (u16*)(ws + (20u << 20));            // 16 MB  [4096][2048]
    u16* Vt      = (u16*)(ws + (36u << 20));            // 8 MB   [2048][2048]
    u16* attno   = (u16*)(ws + (44u << 20));            // 8 MB   [4096][1024]
    u16* Wdqkv_t = (u16*)(ws + (52u << 20));            // 1 MB   [512][1024]
    u16* Wuq_t   = (u16*)(ws + (53u << 20));            // 0.5 MB [1024][256]
    u16* Wukv_t  = (u16*)(ws + (53u << 20) + (512u << 10)); // 1 MB [2048][256]
    u16* Wo_t    = (u16*)(ws + (55u << 20));            // 2 MB   [1024][1024]

    dim3 blk(256);
    // x -> bf16
    cvt_f32_bf16<<<2048, blk, 0, stream>>>(x, xb, TT * DM);
    // weight transposes (fp32 -> bf16, [K][N] -> [N][K])
    transpose_cvt<<<dim3(8, 32),  blk, 0, stream>>>(W_dq,  DM, DC, Wdqkv_t, DM, 0);
    transpose_cvt<<<dim3(8, 32),  blk, 0, stream>>>(W_dkv, DM, DC, Wdqkv_t, DM, DC);
    transpose_cvt<<<dim3(32, 8),  blk, 0, stream>>>(W_uq,  DC, DM, Wuq_t,  DC, 0);
    transpose_cvt<<<dim3(32, 8),  blk, 0, stream>>>(W_uk,  DC, DM, Wukv_t, DC, 0);
    transpose_cvt<<<dim3(32, 8),  blk, 0, stream>>>(W_uv,  DC, DM, Wukv_t, DC, DM);
    transpose_cvt<<<dim3(32, 32), blk, 0, stream>>>(W_o,   DM, DM, Wo_t,   DM, 0);
    // c_qkv = x @ [W_dq | W_dkv]        [4096,512] K=1024
    gemm128<true><<<dim3(4, 32), blk, 0, stream>>>(xb, DM, Wdqkv_t, DM, c_qkv, 512, DM);
    // Q = c_q @ W_uq                    [4096,1024] K=256
    gemm128<true><<<dim3(8, 32), blk, 0, stream>>>(c_qkv, 512, Wuq_t, DC, Qb, DM, DC);
    // KV = c_kv @ [W_uk | W_uv]         [4096,2048] K=256
    gemm128<true><<<dim3(16, 32), blk, 0, stream>>>(c_qkv + DC, 512, Wukv_t, DC, KVb, 2048, DC);
    // Vt[b*16+h][dk][s] = V[b*2048+s][h*64+dk]  (V = KVb cols 1024..2047)
    transpose_u16<<<dim3(32, 64), blk, 0, stream>>>(KVb + DM, 2048, Vt, 2048);
    transpose_u16<<<dim3(32, 64), blk, 0, stream>>>(KVb + (size_t)SS * 2048 + DM, 2048, Vt + (size_t)1024 * 2048, 2048);
    // attention
    attn_mfma<<<dim3(SS / 64, NH, BB), blk, 0, stream>>>(Qb, KVb, Vt, attno);
    // out = attno @ W_o                 [4096,1024] K=1024, fp32 out
    gemm128<false><<<dim3(8, 32), blk, 0, stream>>>(attno, DM, Wo_t, DM, out, DM, DM);
}

// Round 3
// 183.606 us; speedup vs baseline: 12.0465x; 1.2117x over previous
//
#include <hip/hip_runtime.h>
#include <math.h>

#define AS3 __attribute__((address_space(3)))
#define AS1 __attribute__((address_space(1)))

typedef unsigned short u16;
typedef unsigned int u32;
typedef __bf16 bf16_t;
typedef bf16_t bf16x8 __attribute__((ext_vector_type(8)));
typedef float f32x4 __attribute__((ext_vector_type(4)));
typedef float f32x16 __attribute__((ext_vector_type(16)));
typedef unsigned short u16x8 __attribute__((ext_vector_type(8)));
typedef unsigned int u32x4 __attribute__((ext_vector_type(4)));

#define NH 16
#define DK 64
#define DC 256
#define DM 1024
#define BB 2
#define SS 2048
#define TT (BB*SS)

__device__ __forceinline__ u16 f2bf(float f) {
    unsigned u = __builtin_bit_cast(unsigned, f);
    unsigned r = (u + 0x7FFFu + ((u >> 16) & 1u)) >> 16;
    return (u16)r;
}

__device__ __forceinline__ u32 cvtpk_bf16(float a, float b) {
    u32 d;
    asm("v_cvt_pk_bf16_f32 %0, %1, %2" : "=v"(d) : "v"(a), "v"(b));
    return d;
}

__device__ __forceinline__ bf16x8 lds_frag(const char* p) {
    return __builtin_bit_cast(bf16x8, *reinterpret_cast<const u16x8*>(p));
}

// ---------------- prep kernels ----------------

__global__ __launch_bounds__(256) void cvt_f32_bf16(const float* __restrict__ in,
                                                    u16* __restrict__ out, int n) {
    int i = (blockIdx.x * 256 + threadIdx.x) * 8;
    if (i >= n) return;
    float4 v0 = *reinterpret_cast<const float4*>(in + i);
    float4 v1 = *reinterpret_cast<const float4*>(in + i + 4);
    u16x8 o;
    o[0] = f2bf(v0.x); o[1] = f2bf(v0.y); o[2] = f2bf(v0.z); o[3] = f2bf(v0.w);
    o[4] = f2bf(v1.x); o[5] = f2bf(v1.y); o[6] = f2bf(v1.z); o[7] = f2bf(v1.w);
    *reinterpret_cast<u16x8*>(out + i) = o;
}

// out[(c + orow_off)*opitch + r] = bf16(in[r*C + c])
__global__ __launch_bounds__(256) void transpose_cvt(const float* __restrict__ in, int R, int C,
                                                     u16* __restrict__ out, int opitch, int orow_off) {
    __shared__ float t[32][33];
    int c0 = blockIdx.x * 32, r0 = blockIdx.y * 32;
    int tx = threadIdx.x & 31, ty = threadIdx.x >> 5;   // ty 0..7
    #pragma unroll
    for (int p = 0; p < 4; ++p)
        t[ty + 8 * p][tx] = in[(r0 + ty + 8 * p) * C + c0 + tx];
    __syncthreads();
    #pragma unroll
    for (int p = 0; p < 4; ++p)
        out[(c0 + ty + 8 * p + orow_off) * opitch + r0 + tx] = f2bf(t[tx][ty + 8 * p]);
}

// out[c*opitch + r] = in[r*ipitch + c]   (u16)
__global__ __launch_bounds__(256) void transpose_u16(const u16* __restrict__ in, int ipitch,
                                                     u16* __restrict__ out, int opitch) {
    __shared__ u16 t[32][34];
    int c0 = blockIdx.x * 32, r0 = blockIdx.y * 32;
    int tx = threadIdx.x & 31, ty = threadIdx.x >> 5;
    #pragma unroll
    for (int p = 0; p < 4; ++p)
        t[ty + 8 * p][tx] = in[(r0 + ty + 8 * p) * ipitch + c0 + tx];
    __syncthreads();
    #pragma unroll
    for (int p = 0; p < 4; ++p)
        out[(c0 + ty + 8 * p) * opitch + r0 + tx] = t[tx][ty + 8 * p];
}

// ---------------- MFMA GEMM: C[M,N] = A[M,K] @ Bt[N,K]^T ----------------
template <bool OUT_BF16>
__global__ __launch_bounds__(256) void gemm128(const u16* __restrict__ A, int lda,
                                               const u16* __restrict__ Bt, int ldb,
                                               void* __restrict__ C, int ldc, int K) {
    __shared__ u16 As[128 * 32];
    __shared__ u16 Bs[128 * 32];
    const int tid = threadIdx.x;
    const int lane = tid & 63;
    const int w = tid >> 6;
    const int wr = w >> 1, wc = w & 1;
    const int bm = blockIdx.y * 128, bn = blockIdx.x * 128;
    const int l15 = lane & 15, l4 = lane >> 4;

    f32x4 acc[4][4] = {};

    for (int k0 = 0; k0 < K; k0 += 32) {
        #pragma unroll
        for (int i = 0; i < 2; ++i) {
            int db = i * 4096 + w * 1024 + lane * 16;
            int row = db >> 6;
            int kc = (db & 63) >> 1;
            __builtin_amdgcn_global_load_lds(
                (const AS1 void*)(A + (bm + row) * lda + k0 + kc),
                (AS3 void*)((AS3 char*)(AS3 void*)As + i * 4096 + w * 1024), 16, 0, 0);
            __builtin_amdgcn_global_load_lds(
                (const AS1 void*)(Bt + (bn + row) * ldb + k0 + kc),
                (AS3 void*)((AS3 char*)(AS3 void*)Bs + i * 4096 + w * 1024), 16, 0, 0);
        }
        __syncthreads();
        bf16x8 a[4], b[4];
        #pragma unroll
        for (int m = 0; m < 4; ++m)
            a[m] = __builtin_bit_cast(bf16x8,
                *reinterpret_cast<const u16x8*>(&As[(wr * 64 + m * 16 + l15) * 32 + l4 * 8]));
        #pragma unroll
        for (int n = 0; n < 4; ++n)
            b[n] = __builtin_bit_cast(bf16x8,
                *reinterpret_cast<const u16x8*>(&Bs[(wc * 64 + n * 16 + l15) * 32 + l4 * 8]));
        #pragma unroll
        for (int m = 0; m < 4; ++m)
            #pragma unroll
            for (int n = 0; n < 4; ++n)
                acc[m][n] = __builtin_amdgcn_mfma_f32_16x16x32_bf16(a[m], b[n], acc[m][n], 0, 0, 0);
        __syncthreads();
    }
    #pragma unroll
    for (int m = 0; m < 4; ++m) {
        int row = bm + wr * 64 + m * 16 + l4 * 4;
        #pragma unroll
        for (int j = 0; j < 4; ++j) {
            #pragma unroll
            for (int n = 0; n < 4; ++n) {
                int col = bn + wc * 64 + n * 16 + l15;
                if (OUT_BF16)
                    ((u16*)C)[(row + j) * ldc + col] = f2bf(acc[m][n][j]);
                else
                    ((float*)C)[(row + j) * ldc + col] = acc[m][n][j];
            }
        }
    }
}

// ---------------- MFMA causal flash attention v3 ----------------
// Block = (qb, head, b): 128 q-rows, 4 waves x 32 rows. KVBLK=64, 32x32x16 MFMA.
// Swapped QK^T (S^T cols = q = lane&31) -> in-register softmax.
// Swapped PV (O^T = V^T P^T) -> per-lane scalar rescale.
__global__ __launch_bounds__(256) void attn_mfma2(const u16* __restrict__ Qb,
                                                  const u16* __restrict__ KVb,
                                                  const u16* __restrict__ VtG,
                                                  u16* __restrict__ O) {
    __shared__ char lds[32768];
    const int qb = blockIdx.x, head = blockIdx.y, b = blockIdx.z;
    const int tid = threadIdx.x, lane = tid & 63, w = tid >> 6;
    const int l31 = lane & 31, hi = lane >> 5;
    const int r7 = l31 & 7;
    const int bh = b * 16 + head;
    const int qg = qb * 128 + w * 32 + l31;
    const int qmin = qb * 128 + w * 32;
    const int qmax = qmin + 31;
    const int nt = qb * 2 + 2;
    const float c2 = 0.125f * 1.44269504088896340736f;  // scale * log2(e)

    // Q fragments (B-operand of swapped QK^T): Q[q=lane&31][16kc + 8hi + j]
    bf16x8 qf[4];
    {
        const u16* qp = Qb + (size_t)(b * SS + qg) * 1024 + head * 64 + hi * 8;
        #pragma unroll
        for (int kc = 0; kc < 4; ++kc)
            qf[kc] = __builtin_bit_cast(bf16x8, *reinterpret_cast<const u16x8*>(qp + kc * 16));
    }

    f32x16 acc0 = {}, acc1 = {};   // O^T: d-tiles 0..31 / 32..63, col = q
    float mrow = -3.0e38f, lrow = 0.f;

#define STAGE(bufi, kt_) do { \
    int k0_ = (kt_) * 64; \
    _Pragma("unroll") \
    for (int c_ = 0; c_ < 2; ++c_) { \
        int i_ = tid + 256 * c_; int row_ = i_ >> 3; int sc_ = (i_ & 7) ^ (row_ & 7); \
        __builtin_amdgcn_global_load_lds( \
            (const AS1 void*)(KVb + (size_t)(b * SS + k0_ + row_) * 2048 + head * 64 + sc_ * 8), \
            (AS3 void*)((AS3 char*)(AS3 void*)lds + (bufi) * 16384 + c_ * 4096 + w * 1024), 16, 0, 0); \
        __builtin_amdgcn_global_load_lds( \
            (const AS1 void*)(VtG + (size_t)(bh * 64 + row_) * 2048 + k0_ + sc_ * 8), \
            (AS3 void*)((AS3 char*)(AS3 void*)lds + (bufi) * 16384 + 8192 + c_ * 4096 + w * 1024), 16, 0, 0); \
    } } while (0)

    int cur = 0;
    STAGE(0, 0);
    __syncthreads();

    for (int kt = 0; kt < nt; ++kt) {
        if (kt + 1 < nt) STAGE(cur ^ 1, kt + 1);
        if (kt * 64 <= qmax) {
            const char* Kb_ = lds + cur * 16384;
            const char* Vb_ = lds + cur * 16384 + 8192;
            // S^T = K @ Q^T : rows = keys, cols = q
            f32x16 s0 = {}, s1 = {};
            #pragma unroll
            for (int kc = 0; kc < 4; ++kc) {
                bf16x8 kf0 = lds_frag(Kb_ + (l31) * 128 + ((2 * kc + hi) ^ r7) * 16);
                bf16x8 kf1 = lds_frag(Kb_ + (32 + l31) * 128 + ((2 * kc + hi) ^ r7) * 16);
                s0 = __builtin_amdgcn_mfma_f32_32x32x16_bf16(kf0, qf[kc], s0, 0, 0, 0);
                s1 = __builtin_amdgcn_mfma_f32_32x32x16_bf16(kf1, qf[kc], s1, 0, 0, 0);
            }
            if (kt * 64 + 63 > qmin) {   // diagonal: causal mask
                int lim = qg - kt * 64 - hi * 4;
                #pragma unroll
                for (int r = 0; r < 16; ++r) {
                    const int ko = (r & 3) + 8 * (r >> 2);
                    s0[r] = (ko > lim) ? -3.0e38f : s0[r];
                    s1[r] = (ko + 32 > lim) ? -3.0e38f : s1[r];
                }
            }
            // online softmax: full row = 32 in-lane + partner lane (lane^32)
            float tm = -3.0e38f;
            #pragma unroll
            for (int r = 0; r < 16; ++r) tm = fmaxf(tm, fmaxf(s0[r], s1[r]));
            tm = fmaxf(tm, __shfl_xor(tm, 32));
            float mnew = fmaxf(mrow, tm);
            float scale = exp2f((mrow - mnew) * c2);
            float mc = mnew * c2;
            mrow = mnew;
            float rsum = 0.f;
            #pragma unroll
            for (int r = 0; r < 16; ++r) {
                float p0 = exp2f(__builtin_fmaf(s0[r], c2, -mc));
                float p1 = exp2f(__builtin_fmaf(s1[r], c2, -mc));
                s0[r] = p0; s1[r] = p1;
                rsum += p0 + p1;
            }
            rsum += __shfl_xor(rsum, 32);
            lrow = lrow * scale + rsum;
            #pragma unroll
            for (int r = 0; r < 16; ++r) { acc0[r] *= scale; acc1[r] *= scale; }

            // pack P rows to bf16 pairs: cgT[g][w2] = keys 8g+4hi+2*w2+{0,1} (+32*tile)
            u32 cg0[4][2], cg1[4][2];
            #pragma unroll
            for (int g = 0; g < 4; ++g) {
                #pragma unroll
                for (int w2 = 0; w2 < 2; ++w2) {
                    cg0[g][w2] = cvtpk_bf16(s0[4 * g + 2 * w2], s0[4 * g + 2 * w2 + 1]);
                    cg1[g][w2] = cvtpk_bf16(s1[4 * g + 2 * w2], s1[4 * g + 2 * w2 + 1]);
                }
            }
            // assemble P A/B-frags: pa[ks] = P[q=lane&31][16ks + 8hi + 0..7]
            bf16x8 pa[4];
            #pragma unroll
            for (int ks = 0; ks < 4; ++ks) {
                const int g0 = (2 * ks) & 3, g1 = g0 + 1;
                u32 a0, a1, b0, b1;
                if (ks < 2) { a0 = cg0[g0][0]; a1 = cg0[g0][1]; b0 = cg0[g1][0]; b1 = cg0[g1][1]; }
                else        { a0 = cg1[g0][0]; a1 = cg1[g0][1]; b0 = cg1[g1][0]; b1 = cg1[g1][1]; }
                u32 pa0 = (u32)__shfl_xor((int)a0, 32);
                u32 pa1 = (u32)__shfl_xor((int)a1, 32);
                u32 pb0 = (u32)__shfl_xor((int)b0, 32);
                u32 pb1 = (u32)__shfl_xor((int)b1, 32);
                u32x4 f;
                f.x = hi ? pb0 : a0;
                f.y = hi ? pb1 : a1;
                f.z = hi ? b0 : pa0;
                f.w = hi ? b1 : pa1;
                pa[ks] = __builtin_bit_cast(bf16x8, f);
            }
            // O^T += V^T @ P^T : rows = d, cols = q
            #pragma unroll
            for (int ks = 0; ks < 4; ++ks) {
                bf16x8 vf0 = lds_frag(Vb_ + (l31) * 128 + ((2 * ks + hi) ^ r7) * 16);
                bf16x8 vf1 = lds_frag(Vb_ + (32 + l31) * 128 + ((2 * ks + hi) ^ r7) * 16);
                acc0 = __builtin_amdgcn_mfma_f32_32x32x16_bf16(vf0, pa[ks], acc0, 0, 0, 0);
                acc1 = __builtin_amdgcn_mfma_f32_32x32x16_bf16(vf1, pa[ks], acc1, 0, 0, 0);
            }
        }
        __syncthreads();
        cur ^= 1;
    }
#undef STAGE

    // epilogue: normalize, per-wave LDS transpose (pitch 72), coalesced store
    float inv = 1.0f / lrow;
    u16* ot = (u16*)(lds) + w * 2304;   // 32 q-rows x 72 pitch per wave
    #pragma unroll
    for (int i = 0; i < 8; ++i) {
        const int r = 2 * i;
        const int d0 = (r & 3) + 8 * (r >> 2) + 4 * hi;
        *reinterpret_cast<u32*>(&ot[l31 * 72 + d0]) = cvtpk_bf16(acc0[r] * inv, acc0[r + 1] * inv);
        *reinterpret_cast<u32*>(&ot[l31 * 72 + 32 + d0]) = cvtpk_bf16(acc1[r] * inv, acc1[r + 1] * inv);
    }
    asm volatile("s_waitcnt lgkmcnt(0)" ::: "memory");
    __builtin_amdgcn_sched_barrier(0);
    {
        const int q_ = lane >> 1, dh = (lane & 1) * 32;
        const u16* src = ot + q_ * 72 + dh;
        u16* dst = O + (size_t)(b * SS + qb * 128 + w * 32 + q_) * 1024 + head * 64 + dh;
        #pragma unroll
        for (int c = 0; c < 4; ++c)
            *reinterpret_cast<u32x4*>(dst + c * 8) = *reinterpret_cast<const u32x4*>(src + c * 8);
    }
}

// ---------------- launch ----------------

extern "C" void kernel_launch(void* const* d_in, const int* in_sizes, int n_in,
                              void* d_out, int out_size, void* d_ws, size_t ws_size,
                              hipStream_t stream) {
    const float* x     = (const float*)d_in[0];
    const float* W_dq  = (const float*)d_in[1];
    const float* W_uq  = (const float*)d_in[2];
    const float* W_dkv = (const float*)d_in[3];
    const float* W_uk  = (const float*)d_in[4];
    const float* W_uv  = (const float*)d_in[5];
    const float* W_o   = (const float*)d_in[6];
    float* out = (float*)d_out;

    char* ws = (char*)d_ws;
    u16* xb      = (u16*)(ws);                          // 8 MB   [4096][1024]
    u16* c_qkv   = (u16*)(ws + (8u << 20));             // 4 MB   [4096][512]
    u16* Qb      = (u16*)(ws + (12u << 20));            // 8 MB   [4096][1024]
    u16* KVb     = (u16*)(ws + (20u << 20));            // 16 MB  [4096][2048]
    u16* Vt      = (u16*)(ws + (36u << 20));            // 8 MB   [2048][2048]
    u16* attno   = (u16*)(ws + (44u << 20));            // 8 MB   [4096][1024]
    u16* Wdqkv_t = (u16*)(ws + (52u << 20));            // 1 MB   [512][1024]
    u16* Wuq_t   = (u16*)(ws + (53u << 20));            // 0.5 MB [1024][256]
    u16* Wukv_t  = (u16*)(ws + (53u << 20) + (512u << 10)); // 1 MB [2048][256]
    u16* Wo_t    = (u16*)(ws + (55u << 20));            // 2 MB   [1024][1024]

    dim3 blk(256);
    cvt_f32_bf16<<<2048, blk, 0, stream>>>(x, xb, TT * DM);
    transpose_cvt<<<dim3(8, 32),  blk, 0, stream>>>(W_dq,  DM, DC, Wdqkv_t, DM, 0);
    transpose_cvt<<<dim3(8, 32),  blk, 0, stream>>>(W_dkv, DM, DC, Wdqkv_t, DM, DC);
    transpose_cvt<<<dim3(32, 8),  blk, 0, stream>>>(W_uq,  DC, DM, Wuq_t,  DC, 0);
    transpose_cvt<<<dim3(32, 8),  blk, 0, stream>>>(W_uk,  DC, DM, Wukv_t, DC, 0);
    transpose_cvt<<<dim3(32, 8),  blk, 0, stream>>>(W_uv,  DC, DM, Wukv_t, DC, DM);
    transpose_cvt<<<dim3(32, 32), blk, 0, stream>>>(W_o,   DM, DM, Wo_t,   DM, 0);
    // c_qkv = x @ [W_dq | W_dkv]        [4096,512] K=1024
    gemm128<true><<<dim3(4, 32), blk, 0, stream>>>(xb, DM, Wdqkv_t, DM, c_qkv, 512, DM);
    // Q = c_q @ W_uq                    [4096,1024] K=256
    gemm128<true><<<dim3(8, 32), blk, 0, stream>>>(c_qkv, 512, Wuq_t, DC, Qb, DM, DC);
    // KV = c_kv @ [W_uk | W_uv]         [4096,2048] K=256
    gemm128<true><<<dim3(16, 32), blk, 0, stream>>>(c_qkv + DC, 512, Wukv_t, DC, KVb, 2048, DC);
    // Vt[b*16+h][dk][s] = V[b*2048+s][h*64+dk]
    transpose_u16<<<dim3(32, 64), blk, 0, stream>>>(KVb + DM, 2048, Vt, 2048);
    transpose_u16<<<dim3(32, 64), blk, 0, stream>>>(KVb + (size_t)SS * 2048 + DM, 2048, Vt + (size_t)1024 * 2048, 2048);
    // attention (v3)
    attn_mfma2<<<dim3(16, NH, BB), blk, 0, stream>>>(Qb, KVb, Vt, attno);
    // out = attno @ W_o                 [4096,1024] K=1024, fp32 out
    gemm128<false><<<dim3(8, 32), blk, 0, stream>>>(attno, DM, Wo_t, DM, out, DM, DM);
}

// Round 5
// 147.631 us; speedup vs baseline: 14.9820x; 1.2437x over previous
//
#include <hip/hip_runtime.h>
#include <math.h>

#define AS3 __attribute__((address_space(3)))
#define AS1 __attribute__((address_space(1)))

typedef unsigned short u16;
typedef unsigned int u32;
typedef __bf16 bf16_t;
typedef bf16_t bf16x8 __attribute__((ext_vector_type(8)));
typedef float f32x4 __attribute__((ext_vector_type(4)));
typedef float f32x16 __attribute__((ext_vector_type(16)));
typedef unsigned short u16x8 __attribute__((ext_vector_type(8)));
typedef unsigned int u32x4 __attribute__((ext_vector_type(4)));

#define NH 16
#define DK 64
#define DC 256
#define DM 1024
#define BB 2
#define SS 2048
#define TT (BB*SS)

__device__ __forceinline__ u16 f2bf(float f) {
    unsigned u = __builtin_bit_cast(unsigned, f);
    unsigned r = (u + 0x7FFFu + ((u >> 16) & 1u)) >> 16;
    return (u16)r;
}

__device__ __forceinline__ u32 cvtpk_bf16(float a, float b) {
    u32 d;
    asm("v_cvt_pk_bf16_f32 %0, %1, %2" : "=v"(d) : "v"(a), "v"(b));
    return d;
}

__device__ __forceinline__ bf16x8 lds_frag(const char* p) {
    return __builtin_bit_cast(bf16x8, *reinterpret_cast<const u16x8*>(p));
}

// ---------------- fused prep: x->bf16 (z=6) + 6 weight transposes (z=0..5) ----------------
__global__ __launch_bounds__(256) void prep(const float* __restrict__ x, u16* __restrict__ xb,
                                            const float* w0, const float* w1, const float* w2,
                                            const float* w3, const float* w4, const float* w5,
                                            u16* d0, u16* d1, u16* d2, u16* d3, u16* d4, u16* d5) {
    __shared__ float t[32][33];
    const int z = blockIdx.z;
    if (z == 6) {   // x conversion: 1024 blocks x 256 th x 16 elems
        int blk = blockIdx.y * 32 + blockIdx.x;
        int i = (blk * 256 + threadIdx.x) * 16;
        float4 v0 = *reinterpret_cast<const float4*>(x + i);
        float4 v1 = *reinterpret_cast<const float4*>(x + i + 4);
        float4 v2 = *reinterpret_cast<const float4*>(x + i + 8);
        float4 v3 = *reinterpret_cast<const float4*>(x + i + 12);
        u16x8 o0, o1;
        o0[0] = f2bf(v0.x); o0[1] = f2bf(v0.y); o0[2] = f2bf(v0.z); o0[3] = f2bf(v0.w);
        o0[4] = f2bf(v1.x); o0[5] = f2bf(v1.y); o0[6] = f2bf(v1.z); o0[7] = f2bf(v1.w);
        o1[0] = f2bf(v2.x); o1[1] = f2bf(v2.y); o1[2] = f2bf(v2.z); o1[3] = f2bf(v2.w);
        o1[4] = f2bf(v3.x); o1[5] = f2bf(v3.y); o1[6] = f2bf(v3.z); o1[7] = f2bf(v3.w);
        *reinterpret_cast<u16x8*>(xb + i) = o0;
        *reinterpret_cast<u16x8*>(xb + i + 8) = o1;
        return;
    }
    const float* src; u16* dst; int R, C, opitch;
    switch (z) {
        case 0:  src = w0; dst = d0; R = 1024; C = 256;  opitch = 1024; break;
        case 1:  src = w1; dst = d1; R = 1024; C = 256;  opitch = 1024; break;
        case 2:  src = w2; dst = d2; R = 256;  C = 1024; opitch = 256;  break;
        case 3:  src = w3; dst = d3; R = 256;  C = 1024; opitch = 256;  break;
        case 4:  src = w4; dst = d4; R = 256;  C = 1024; opitch = 256;  break;
        default: src = w5; dst = d5; R = 1024; C = 1024; opitch = 1024; break;
    }
    int c0 = blockIdx.x * 32, r0 = blockIdx.y * 32;
    if (c0 >= C || r0 >= R) return;
    int tx = threadIdx.x & 31, ty = threadIdx.x >> 5;
    #pragma unroll
    for (int p = 0; p < 4; ++p)
        t[ty + 8 * p][tx] = src[(r0 + ty + 8 * p) * C + c0 + tx];
    __syncthreads();
    #pragma unroll
    for (int p = 0; p < 4; ++p)
        dst[(c0 + ty + 8 * p) * opitch + r0 + tx] = f2bf(t[tx][ty + 8 * p]);
}

// ---------------- MFMA GEMM: C[M,N] = A[M,K] @ Bt[N,K]^T, 128xBN tile ----------------
template <int BN, bool OUT_BF16>
__global__ __launch_bounds__(256) void gemmT(const u16* __restrict__ A, int lda,
                                             const u16* __restrict__ Bt, int ldb,
                                             void* __restrict__ C, int ldc, int K) {
    constexpr int NF = BN / 32;   // frags per wave in N
    constexpr int BI = BN / 64;   // B staging iterations
    __shared__ u16 As[128 * 32];
    __shared__ u16 Bs[BN * 32];
    const int tid = threadIdx.x;
    const int lane = tid & 63;
    const int w = tid >> 6;
    const int wr = w >> 1, wc = w & 1;
    const int bm = blockIdx.y * 128, bn = blockIdx.x * BN;
    const int l15 = lane & 15, l4 = lane >> 4;

    f32x4 acc[4][NF] = {};

    for (int k0 = 0; k0 < K; k0 += 32) {
        #pragma unroll
        for (int i = 0; i < 2; ++i) {
            int db = i * 4096 + tid * 16;
            int row = db >> 6;
            int kc = (db & 63) >> 1;
            __builtin_amdgcn_global_load_lds(
                (const AS1 void*)(A + (bm + row) * lda + k0 + kc),
                (AS3 void*)((AS3 char*)(AS3 void*)As + i * 4096 + w * 1024), 16, 0, 0);
        }
        #pragma unroll
        for (int i = 0; i < BI; ++i) {
            int db = i * 4096 + tid * 16;
            int row = db >> 6;
            int kc = (db & 63) >> 1;
            __builtin_amdgcn_global_load_lds(
                (const AS1 void*)(Bt + (bn + row) * ldb + k0 + kc),
                (AS3 void*)((AS3 char*)(AS3 void*)Bs + i * 4096 + w * 1024), 16, 0, 0);
        }
        __syncthreads();
        bf16x8 a[4], b[NF];
        #pragma unroll
        for (int m = 0; m < 4; ++m)
            a[m] = __builtin_bit_cast(bf16x8,
                *reinterpret_cast<const u16x8*>(&As[(wr * 64 + m * 16 + l15) * 32 + l4 * 8]));
        #pragma unroll
        for (int n = 0; n < NF; ++n)
            b[n] = __builtin_bit_cast(bf16x8,
                *reinterpret_cast<const u16x8*>(&Bs[(wc * (BN / 2) + n * 16 + l15) * 32 + l4 * 8]));
        #pragma unroll
        for (int m = 0; m < 4; ++m)
            #pragma unroll
            for (int n = 0; n < NF; ++n)
                acc[m][n] = __builtin_amdgcn_mfma_f32_16x16x32_bf16(a[m], b[n], acc[m][n], 0, 0, 0);
        __syncthreads();
    }
    #pragma unroll
    for (int m = 0; m < 4; ++m) {
        int row = bm + wr * 64 + m * 16 + l4 * 4;
        #pragma unroll
        for (int j = 0; j < 4; ++j) {
            #pragma unroll
            for (int n = 0; n < NF; ++n) {
                int col = bn + wc * (BN / 2) + n * 16 + l15;
                if (OUT_BF16)
                    ((u16*)C)[(row + j) * ldc + col] = f2bf(acc[m][n][j]);
                else
                    ((float*)C)[(row + j) * ldc + col] = acc[m][n][j];
            }
        }
    }
}

// ---------------- V transpose: Vt[b*1024 + c][s] = KVb[b*2048+s][1024+c] ----------------
__global__ __launch_bounds__(256) void vt_kernel(const u16* __restrict__ KVb, u16* __restrict__ Vt) {
    __shared__ u16 t[32][34];
    const int bb = blockIdx.z;
    const u16* in = KVb + (size_t)bb * SS * 2048 + 1024;
    u16* out = Vt + (size_t)bb * 1024 * 2048;
    int c0 = blockIdx.x * 32, r0 = blockIdx.y * 32;
    int tx = threadIdx.x & 31, ty = threadIdx.x >> 5;
    #pragma unroll
    for (int p = 0; p < 4; ++p)
        t[ty + 8 * p][tx] = in[(size_t)(r0 + ty + 8 * p) * 2048 + c0 + tx];
    __syncthreads();
    #pragma unroll
    for (int p = 0; p < 4; ++p)
        out[(size_t)(c0 + ty + 8 * p) * 2048 + r0 + tx] = t[tx][ty + 8 * p];
}

// ---------------- MFMA causal flash attention v5 ----------------
// 1D grid 512; balanced remap: qb = (L>>8)? 15-(L&15) : (L&15) so CU pairs get equal work.
// Swapped QK^T / swapped PV; cross-half exchanges via __shfl_xor(32) (verified R3 path).
__global__ __launch_bounds__(256) void attn_mfma3(const u16* __restrict__ Qb,
                                                  const u16* __restrict__ KVb,
                                                  const u16* __restrict__ VtG,
                                                  u16* __restrict__ O) {
    __shared__ char lds[32768];
    const int L = blockIdx.x;
    const int b = L >> 8;
    const int head = (L >> 4) & 15;
    const int u = L & 15;
    const int qb = b ? (15 - u) : u;
    const int tid = threadIdx.x, lane = tid & 63, w = tid >> 6;
    const int l31 = lane & 31, hi = lane >> 5;
    const int r7 = l31 & 7;
    const int bh = b * 16 + head;
    const int qg = qb * 128 + w * 32 + l31;
    const int qmin = qb * 128 + w * 32;
    const int qmax = qmin + 31;
    const int nt = qb * 2 + 2;
    const float c2 = 0.125f * 1.44269504088896340736f;  // scale * log2(e)
    const float THRraw = 44.3614195558f;                // 8 / c2 (defer-max threshold)

    // Q fragments (B-operand of swapped QK^T): Q[q=lane&31][16kc + 8hi + j]
    bf16x8 qf[4];
    {
        const u16* qp = Qb + (size_t)(b * SS + qg) * 1024 + head * 64 + hi * 8;
        #pragma unroll
        for (int kc = 0; kc < 4; ++kc)
            qf[kc] = __builtin_bit_cast(bf16x8, *reinterpret_cast<const u16x8*>(qp + kc * 16));
    }

    f32x16 acc0 = {}, acc1 = {};   // O^T: d-tiles 0..31 / 32..63, col = q
    float mrow = -3.0e38f, lrow = 0.f;

#define STAGE(bufi, kt_) do { \
    int k0_ = (kt_) * 64; \
    _Pragma("unroll") \
    for (int c_ = 0; c_ < 2; ++c_) { \
        int i_ = tid + 256 * c_; int row_ = i_ >> 3; int sc_ = (i_ & 7) ^ (row_ & 7); \
        __builtin_amdgcn_global_load_lds( \
            (const AS1 void*)(KVb + (size_t)(b * SS + k0_ + row_) * 2048 + head * 64 + sc_ * 8), \
            (AS3 void*)((AS3 char*)(AS3 void*)lds + (bufi) * 16384 + c_ * 4096 + w * 1024), 16, 0, 0); \
        __builtin_amdgcn_global_load_lds( \
            (const AS1 void*)(VtG + (size_t)(bh * 64 + row_) * 2048 + k0_ + sc_ * 8), \
            (AS3 void*)((AS3 char*)(AS3 void*)lds + (bufi) * 16384 + 8192 + c_ * 4096 + w * 1024), 16, 0, 0); \
    } } while (0)

    int cur = 0;
    STAGE(0, 0);
    __syncthreads();

    for (int kt = 0; kt < nt; ++kt) {
        if (kt + 1 < nt) STAGE(cur ^ 1, kt + 1);
        if (kt * 64 <= qmax) {
            const char* Kb_ = lds + cur * 16384;
            const char* Vb_ = lds + cur * 16384 + 8192;
            // S^T = K @ Q^T : rows = keys, cols = q
            f32x16 s0 = {}, s1 = {};
            __builtin_amdgcn_s_setprio(1);
            #pragma unroll
            for (int kc = 0; kc < 4; ++kc) {
                bf16x8 kf0 = lds_frag(Kb_ + (l31) * 128 + ((2 * kc + hi) ^ r7) * 16);
                bf16x8 kf1 = lds_frag(Kb_ + (32 + l31) * 128 + ((2 * kc + hi) ^ r7) * 16);
                s0 = __builtin_amdgcn_mfma_f32_32x32x16_bf16(kf0, qf[kc], s0, 0, 0, 0);
                s1 = __builtin_amdgcn_mfma_f32_32x32x16_bf16(kf1, qf[kc], s1, 0, 0, 0);
            }
            __builtin_amdgcn_s_setprio(0);
            if (kt * 64 + 63 > qmin) {   // diagonal: causal mask
                int lim = qg - kt * 64 - hi * 4;
                #pragma unroll
                for (int r = 0; r < 16; ++r) {
                    const int ko = (r & 3) + 8 * (r >> 2);
                    s0[r] = (ko > lim) ? -3.0e38f : s0[r];
                    s1[r] = (ko + 32 > lim) ? -3.0e38f : s1[r];
                }
            }
            // tree max over 32 in-lane values, then cross-half exchange
            float a8[8];
            #pragma unroll
            for (int i = 0; i < 8; ++i)
                a8[i] = fmaxf(fmaxf(s0[2 * i], s0[2 * i + 1]), fmaxf(s1[2 * i], s1[2 * i + 1]));
            float tm = fmaxf(fmaxf(fmaxf(a8[0], a8[1]), fmaxf(a8[2], a8[3])),
                             fmaxf(fmaxf(a8[4], a8[5]), fmaxf(a8[6], a8[7])));
            tm = fmaxf(tm, __shfl_xor(tm, 32));
            // defer-max: skip rescale when max growth bounded (P <= 2^8)
            bool nofix = __all(tm <= mrow + THRraw);
            float scale = 1.f;
            if (!nofix) {
                float mnew = fmaxf(mrow, tm);
                scale = exp2f((mrow - mnew) * c2);
                mrow = mnew;
            }
            float mc = mrow * c2;
            #pragma unroll
            for (int r = 0; r < 16; ++r) {
                s0[r] = exp2f(__builtin_fmaf(s0[r], c2, -mc));
                s1[r] = exp2f(__builtin_fmaf(s1[r], c2, -mc));
            }
            // tree sum + cross-half exchange
            float c8[8];
            #pragma unroll
            for (int i = 0; i < 8; ++i)
                c8[i] = (s0[2 * i] + s0[2 * i + 1]) + (s1[2 * i] + s1[2 * i + 1]);
            float rsum = ((c8[0] + c8[1]) + (c8[2] + c8[3])) + ((c8[4] + c8[5]) + (c8[6] + c8[7]));
            rsum += __shfl_xor(rsum, 32);
            if (nofix) {
                lrow += rsum;
            } else {
                lrow = lrow * scale + rsum;
                #pragma unroll
                for (int r = 0; r < 16; ++r) { acc0[r] *= scale; acc1[r] *= scale; }
            }
            // pack P rows to bf16 pairs: cg[g][w2] = keys 8g+4hi+2w2+{0,1} (+32 for s1)
            u32 cg0[4][2], cg1[4][2];
            #pragma unroll
            for (int g = 0; g < 4; ++g) {
                #pragma unroll
                for (int w2 = 0; w2 < 2; ++w2) {
                    cg0[g][w2] = cvtpk_bf16(s0[4 * g + 2 * w2], s0[4 * g + 2 * w2 + 1]);
                    cg1[g][w2] = cvtpk_bf16(s1[4 * g + 2 * w2], s1[4 * g + 2 * w2 + 1]);
                }
            }
            // assemble P frags via shfl_xor(32): pa[ks] = P[q][16ks + 8hi + 0..7]
            bf16x8 pa[4];
            #pragma unroll
            for (int ks = 0; ks < 4; ++ks) {
                const int g0 = (2 * ks) & 3, g1 = g0 + 1;
                u32 a0, a1, b0, b1;
                if (ks < 2) { a0 = cg0[g0][0]; a1 = cg0[g0][1]; b0 = cg0[g1][0]; b1 = cg0[g1][1]; }
                else        { a0 = cg1[g0][0]; a1 = cg1[g0][1]; b0 = cg1[g1][0]; b1 = cg1[g1][1]; }
                u32 pa0 = (u32)__shfl_xor((int)a0, 32);
                u32 pa1 = (u32)__shfl_xor((int)a1, 32);
                u32 pb0 = (u32)__shfl_xor((int)b0, 32);
                u32 pb1 = (u32)__shfl_xor((int)b1, 32);
                u32x4 f;
                f.x = hi ? pb0 : a0;
                f.y = hi ? pb1 : a1;
                f.z = hi ? b0 : pa0;
                f.w = hi ? b1 : pa1;
                pa[ks] = __builtin_bit_cast(bf16x8, f);
            }
            // O^T += V^T @ P^T : rows = d, cols = q
            __builtin_amdgcn_s_setprio(1);
            #pragma unroll
            for (int ks = 0; ks < 4; ++ks) {
                bf16x8 vf0 = lds_frag(Vb_ + (l31) * 128 + ((2 * ks + hi) ^ r7) * 16);
                bf16x8 vf1 = lds_frag(Vb_ + (32 + l31) * 128 + ((2 * ks + hi) ^ r7) * 16);
                acc0 = __builtin_amdgcn_mfma_f32_32x32x16_bf16(vf0, pa[ks], acc0, 0, 0, 0);
                acc1 = __builtin_amdgcn_mfma_f32_32x32x16_bf16(vf1, pa[ks], acc1, 0, 0, 0);
            }
            __builtin_amdgcn_s_setprio(0);
        }
        __syncthreads();
        cur ^= 1;
    }
#undef STAGE

    // epilogue: normalize, per-wave LDS transpose (pitch 72), coalesced store
    float inv = 1.0f / lrow;
    u16* ot = (u16*)(lds) + w * 2304;   // 32 q-rows x 72 pitch per wave
    #pragma unroll
    for (int i = 0; i < 8; ++i) {
        const int r = 2 * i;
        const int d0 = (r & 3) + 8 * (r >> 2) + 4 * hi;
        *reinterpret_cast<u32*>(&ot[l31 * 72 + d0]) = cvtpk_bf16(acc0[r] * inv, acc0[r + 1] * inv);
        *reinterpret_cast<u32*>(&ot[l31 * 72 + 32 + d0]) = cvtpk_bf16(acc1[r] * inv, acc1[r + 1] * inv);
    }
    asm volatile("s_waitcnt lgkmcnt(0)" ::: "memory");
    __builtin_amdgcn_sched_barrier(0);
    {
        const int q_ = lane >> 1, dh = (lane & 1) * 32;
        const u16* src = ot + q_ * 72 + dh;
        u16* dst = O + (size_t)(b * SS + qb * 128 + w * 32 + q_) * 1024 + head * 64 + dh;
        #pragma unroll
        for (int c = 0; c < 4; ++c)
            *reinterpret_cast<u32x4*>(dst + c * 8) = *reinterpret_cast<const u32x4*>(src + c * 8);
    }
}

// ---------------- launch ----------------

extern "C" void kernel_launch(void* const* d_in, const int* in_sizes, int n_in,
                              void* d_out, int out_size, void* d_ws, size_t ws_size,
                              hipStream_t stream) {
    const float* x     = (const float*)d_in[0];
    const float* W_dq  = (const float*)d_in[1];
    const float* W_uq  = (const float*)d_in[2];
    const float* W_dkv = (const float*)d_in[3];
    const float* W_uk  = (const float*)d_in[4];
    const float* W_uv  = (const float*)d_in[5];
    const float* W_o   = (const float*)d_in[6];
    float* out = (float*)d_out;

    char* ws = (char*)d_ws;
    u16* xb      = (u16*)(ws);                          // 8 MB   [4096][1024]
    u16* c_qkv   = (u16*)(ws + (8u << 20));             // 4 MB   [4096][512]
    u16* Qb      = (u16*)(ws + (12u << 20));            // 8 MB   [4096][1024]
    u16* KVb     = (u16*)(ws + (20u << 20));            // 16 MB  [4096][2048]
    u16* Vt      = (u16*)(ws + (36u << 20));            // 8 MB   [2048][2048]
    u16* attno   = (u16*)(ws + (44u << 20));            // 8 MB   [4096][1024]
    u16* Wdqkv_t = (u16*)(ws + (52u << 20));            // 1 MB   [512][1024]
    u16* Wuq_t   = (u16*)(ws + (53u << 20));            // 0.5 MB [1024][256]
    u16* Wukv_t  = (u16*)(ws + (53u << 20) + (512u << 10)); // 1 MB [2048][256]
    u16* Wo_t    = (u16*)(ws + (55u << 20));            // 2 MB   [1024][1024]

    dim3 blk(256);
    prep<<<dim3(32, 32, 7), blk, 0, stream>>>(x, xb, W_dq, W_dkv, W_uq, W_uk, W_uv, W_o,
        Wdqkv_t, Wdqkv_t + 256 * 1024, Wuq_t, Wukv_t, Wukv_t + 1024 * 256, Wo_t);
    // c_qkv = x @ [W_dq | W_dkv]        [4096,512] K=1024
    gemmT<64, true><<<dim3(8, 32), blk, 0, stream>>>(xb, DM, Wdqkv_t, DM, c_qkv, 512, DM);
    // Q = c_q @ W_uq                    [4096,1024] K=256
    gemmT<128, true><<<dim3(8, 32), blk, 0, stream>>>(c_qkv, 512, Wuq_t, DC, Qb, DM, DC);
    // KV = c_kv @ [W_uk | W_uv]         [4096,2048] K=256
    gemmT<128, true><<<dim3(16, 32), blk, 0, stream>>>(c_qkv + DC, 512, Wukv_t, DC, KVb, 2048, DC);
    // Vt[b*16+h][dk][s] = V[b*2048+s][h*64+dk]
    vt_kernel<<<dim3(32, 64, 2), blk, 0, stream>>>(KVb, Vt);
    // attention (balanced 1D grid)
    attn_mfma3<<<dim3(512), blk, 0, stream>>>(Qb, KVb, Vt, attno);
    // out = attno @ W_o                 [4096,1024] K=1024, fp32 out
    gemmT<128, false><<<dim3(8, 32), blk, 0, stream>>>(attno, DM, Wo_t, DM, out, DM, DM);
}